// Round 1
// baseline (89.743 us; speedup 1.0000x reference)
//
#include <hip/hip_runtime.h>
#include <hip/hip_bf16.h>
#include <cstdint>

// Problem dims (fixed by the reference):
//   x: [8, 8192, 512] f32 -> LN over E=512 -> view as [16384, 2048]
//   W: [2048, 512] f32, b: [512]
//   out: [16384, 512] f32 = gelu_exact(h @ W + b)
#define XROWS   65536      // 8*8192
#define E       512
#define MROWS   16384      // XROWS/4
#define KDIM    2048       // 4*E
#define NDIM    512

typedef __attribute__((ext_vector_type(4))) float f32x4;
typedef __attribute__((ext_vector_type(8))) unsigned short u16x8;
typedef __attribute__((ext_vector_type(8))) __bf16 bf16x8;

__device__ __forceinline__ unsigned short f2bf(float f) {
  unsigned u = __builtin_bit_cast(unsigned, f);
  u += 0x7FFFu + ((u >> 16) & 1u);   // round-to-nearest-even
  return (unsigned short)(u >> 16);
}

// ---------------------------------------------------------------------------
// W [2048][512] f32 -> WT [512][2048] bf16 (so GEMM B-frags are k-contiguous)
// grid: 256 blocks (32 k-tiles x 8 n-tiles), 256 threads
// ---------------------------------------------------------------------------
__global__ __launch_bounds__(256) void wt_kernel(const float* __restrict__ W,
                                                 unsigned short* __restrict__ WT) {
  __shared__ float tile[64][68];   // +4 pad breaks transpose-read conflicts
  const int t  = threadIdx.x;
  const int bk = blockIdx.x >> 3;  // k-tile 0..31
  const int bn = blockIdx.x & 7;   // n-tile 0..7
  const int c4 = (t & 15) * 4;
#pragma unroll
  for (int i = 0; i < 4; ++i) {
    const int r = (t >> 4) + i * 16;
    const f32x4 v = *(const f32x4*)&W[(size_t)(bk * 64 + r) * NDIM + bn * 64 + c4];
    tile[r][c4 + 0] = v.x; tile[r][c4 + 1] = v.y;
    tile[r][c4 + 2] = v.z; tile[r][c4 + 3] = v.w;
  }
  __syncthreads();
#pragma unroll
  for (int j = 0; j < 2; ++j) {
    const int n  = j * 32 + (t >> 3);
    const int kb = (t & 7) * 8;
    u16x8 o;
#pragma unroll
    for (int q = 0; q < 8; ++q) o[q] = f2bf(tile[kb + q][n]);
    *(u16x8*)&WT[(size_t)(bn * 64 + n) * KDIM + bk * 64 + kb] = o;
  }
}

// ---------------------------------------------------------------------------
// LayerNorm: one wave per row of 512 f32 -> bf16
// ---------------------------------------------------------------------------
__global__ __launch_bounds__(256, 4) void ln_kernel(const float* __restrict__ x,
                                                    const float* __restrict__ gamma,
                                                    const float* __restrict__ beta,
                                                    unsigned short* __restrict__ h) {
  const int w = threadIdx.x >> 6, l = threadIdx.x & 63;
  const size_t row = (size_t)blockIdx.x * 4 + w;
  const float* xr = x + row * E + l * 8;
  const f32x4 v0 = *(const f32x4*)xr;
  const f32x4 v1 = *(const f32x4*)(xr + 4);
  float xv[8] = {v0.x, v0.y, v0.z, v0.w, v1.x, v1.y, v1.z, v1.w};
  float s = 0.f, q = 0.f;
#pragma unroll
  for (int j = 0; j < 8; ++j) { s += xv[j]; q += xv[j] * xv[j]; }
#pragma unroll
  for (int off = 32; off > 0; off >>= 1) {
    s += __shfl_xor(s, off);
    q += __shfl_xor(q, off);
  }
  const float mean = s * (1.0f / E);
  const float var  = q * (1.0f / E) - mean * mean;
  const float rstd = rsqrtf(var + 1e-6f);
  const f32x4 g0 = *(const f32x4*)(gamma + l * 8);
  const f32x4 g1 = *(const f32x4*)(gamma + l * 8 + 4);
  const f32x4 b0 = *(const f32x4*)(beta + l * 8);
  const f32x4 b1 = *(const f32x4*)(beta + l * 8 + 4);
  const float gv[8] = {g0.x, g0.y, g0.z, g0.w, g1.x, g1.y, g1.z, g1.w};
  const float bv[8] = {b0.x, b0.y, b0.z, b0.w, b1.x, b1.y, b1.z, b1.w};
  u16x8 o;
#pragma unroll
  for (int j = 0; j < 8; ++j) o[j] = f2bf((xv[j] - mean) * rstd * gv[j] + bv[j]);
  *(u16x8*)(h + row * E + l * 8) = o;
}

// ---------------------------------------------------------------------------
// GEMM: A[h, Mc x 2048 bf16] x WT[512 x 2048 bf16] -> out f32, fused bias+gelu
// 128x128 tile, BK=64, 4 waves (2x2), mfma_f32_16x16x32_bf16
// LDS XOR-swizzle (T2): byte_col ^= (row&7)<<4, applied on write AND read.
// Double-buffered LDS, one __syncthreads per K-step, reg-staged global loads
// issued one step ahead (latency hidden under MFMA of current step).
// ---------------------------------------------------------------------------
#define NT (KDIM / 64)   // 32 K-steps

__global__ __launch_bounds__(256, 2) void gemm_kernel(const unsigned short* __restrict__ A,
                                                      const unsigned short* __restrict__ Bt,
                                                      const float* __restrict__ bias,
                                                      float* __restrict__ out) {
  __shared__ char smem[2 * 32768];   // buf{0,1}: A 16KB + B 16KB
  const int tid = threadIdx.x;
  const int l = tid & 63, w = tid >> 6;
  const int l7 = l & 7, l15 = l & 15, lhi = l >> 4;
  const int wr = w >> 1, wc = w & 1;

  const int bn = blockIdx.x & 3;         // 4 N-tiles
  const int bm = blockIdx.x >> 2;
  const size_t arow0 = (size_t)bm * 128;
  const int    brow0 = bn * 128;

  // staging: thread covers rows {i*32 + w*8 + (l>>3)}, k-bytes (l&7)*16
  const int srow = w * 8 + (l >> 3);
  const int scol = l7 * 8;                                   // k element
  const int swz  = (l7 * 16) ^ (((l >> 3) & 7) << 4);        // swizzled byte col
  const unsigned short* gA = A  + ((size_t)(arow0 + srow)) * KDIM + scol;
  const unsigned short* gB = Bt + ((size_t)(brow0 + srow)) * KDIM + scol;

  u16x8 ra[4], rb[4];

  auto load_regs = [&](int t) {
    const unsigned short* pa = gA + t * 64;
    const unsigned short* pb = gB + t * 64;
#pragma unroll
    for (int i = 0; i < 4; ++i) {
      ra[i] = *(const u16x8*)(pa + (size_t)i * 32 * KDIM);
      rb[i] = *(const u16x8*)(pb + (size_t)i * 32 * KDIM);
    }
  };
  auto store_lds = [&](int buf) {
    char* base = smem + buf * 32768;
#pragma unroll
    for (int i = 0; i < 4; ++i) {
      const int r = i * 32 + srow;
      *(u16x8*)(base + r * 128 + swz)         = ra[i];
      *(u16x8*)(base + 16384 + r * 128 + swz) = rb[i];
    }
  };

  f32x4 acc[4][4];
#pragma unroll
  for (int m = 0; m < 4; ++m)
#pragma unroll
    for (int n = 0; n < 4; ++n) acc[m][n] = (f32x4){0.f, 0.f, 0.f, 0.f};

  // frag-read swizzled k-byte for kk=0; kk=32 is ^64 (bit6 only ever from XOR)
  const int cs0 = (lhi * 16) ^ (l7 * 16);

  load_regs(0);
  store_lds(0);
  load_regs(1);
  __syncthreads();

  for (int t = 0; t < NT; ++t) {
    const char* Ab = smem + (t & 1) * 32768;
    const char* Bb = Ab + 16384;
#pragma unroll
    for (int kk = 0; kk < 2; ++kk) {
      const int co = cs0 ^ (kk * 64);
      bf16x8 av[4], bv[4];
#pragma unroll
      for (int m = 0; m < 4; ++m)
        av[m] = *(const bf16x8*)(Ab + (wr * 64 + m * 16 + l15) * 128 + co);
#pragma unroll
      for (int n = 0; n < 4; ++n)
        bv[n] = *(const bf16x8*)(Bb + (wc * 64 + n * 16 + l15) * 128 + co);
#pragma unroll
      for (int m = 0; m < 4; ++m)
#pragma unroll
        for (int n = 0; n < 4; ++n)
          acc[m][n] = __builtin_amdgcn_mfma_f32_16x16x32_bf16(av[m], bv[n], acc[m][n], 0, 0, 0);
    }
    if (t + 1 < NT) {
      store_lds((t + 1) & 1);        // regs for t+1 were loaded one step ago
      if (t + 2 < NT) load_regs(t + 2);
      __syncthreads();               // buf[t+1] ready; buf[t] free next step
    }
  }

  // epilogue: bias + exact gelu, f32 store
  // C/D layout (verified m89): col = l&15, row = (l>>4)*4 + reg
#pragma unroll
  for (int n = 0; n < 4; ++n) {
    const int col = brow0 + wc * 64 + n * 16 + l15;
    const float bb = bias[col];
#pragma unroll
    for (int m = 0; m < 4; ++m) {
      const size_t rbase = arow0 + wr * 64 + m * 16 + lhi * 4;
#pragma unroll
      for (int r = 0; r < 4; ++r) {
        const float v = acc[m][n][r] + bb;
        const float ge = 0.5f * v * (1.0f + erff(v * 0.70710678118654752f));
        out[(rbase + r) * NDIM + col] = ge;
      }
    }
  }
}

// ---------------------------------------------------------------------------
extern "C" void kernel_launch(void* const* d_in, const int* in_sizes, int n_in,
                              void* d_out, int out_size, void* d_ws, size_t ws_size,
                              hipStream_t stream) {
  const float* x     = (const float*)d_in[0];
  const float* gamma = (const float*)d_in[1];
  const float* beta  = (const float*)d_in[2];
  const float* W     = (const float*)d_in[3];
  const float* bias  = (const float*)d_in[4];
  float* out = (float*)d_out;

  unsigned short* WT = (unsigned short*)d_ws;          // 2 MiB
  const size_t wtBytes = (size_t)NDIM * KDIM * 2;
  unsigned short* h = (unsigned short*)((char*)d_ws + wtBytes);

  // chunk M if workspace can't hold the full 64 MiB h buffer
  int NC = 1;
  while (NC < 64 && wtBytes + ((size_t)MROWS / NC) * KDIM * 2 > ws_size) NC <<= 1;
  const int Mc = MROWS / NC;

  wt_kernel<<<256, 256, 0, stream>>>(W, WT);
  for (int c = 0; c < NC; ++c) {
    const float* xc = x + (size_t)c * Mc * KDIM;       // Mc*4 x-rows * 512
    ln_kernel<<<Mc, 256, 0, stream>>>(xc, gamma, beta, h);
    gemm_kernel<<<(Mc / 128) * 4, 256, 0, stream>>>(h, WT, bias,
                                                    out + (size_t)c * Mc * NDIM);
  }
}

// Round 2
// 87.924 us; speedup vs baseline: 1.0207x; 1.0207x over previous
//
#include <hip/hip_runtime.h>
#include <hip/hip_bf16.h>
#include <cstdint>

// Problem dims (fixed by the reference):
//   x: [8, 8192, 512] f32 -> LN over E=512 -> view as [16384, 2048]
//   W: [2048, 512] f32, b: [512]
//   out: [16384, 512] f32 = gelu_exact(h @ W + b)
#define XROWS   65536      // 8*8192
#define E       512
#define MROWS   16384      // XROWS/4
#define KDIM    2048       // 4*E
#define NDIM    512

typedef __attribute__((ext_vector_type(4))) float f32x4;
typedef __attribute__((ext_vector_type(8))) unsigned short u16x8;
typedef __attribute__((ext_vector_type(8))) __bf16 bf16x8;

__device__ __forceinline__ unsigned short f2bf(float f) {
  unsigned u = __builtin_bit_cast(unsigned, f);
  u += 0x7FFFu + ((u >> 16) & 1u);   // round-to-nearest-even
  return (unsigned short)(u >> 16);
}

// async global->LDS, 16B per lane; LDS dest is wave-uniform base + lane*16
typedef const __attribute__((address_space(1))) unsigned char ga_u8;
typedef __attribute__((address_space(3))) unsigned char ls_u8;
__device__ __forceinline__ void gload16(const void* g, void* l) {
  __builtin_amdgcn_global_load_lds((ga_u8*)g, (ls_u8*)l, 16, 0, 0);
}

// ---------------------------------------------------------------------------
// W [2048][512] f32 -> WT [512][2048] bf16 (so GEMM B-frags are k-contiguous)
// grid: 256 blocks (32 k-tiles x 8 n-tiles), 256 threads
// ---------------------------------------------------------------------------
__global__ __launch_bounds__(256) void wt_kernel(const float* __restrict__ W,
                                                 unsigned short* __restrict__ WT) {
  __shared__ float tile[64][68];   // +4 pad breaks transpose-read conflicts
  const int t  = threadIdx.x;
  const int bk = blockIdx.x >> 3;  // k-tile 0..31
  const int bn = blockIdx.x & 7;   // n-tile 0..7
  const int c4 = (t & 15) * 4;
#pragma unroll
  for (int i = 0; i < 4; ++i) {
    const int r = (t >> 4) + i * 16;
    const f32x4 v = *(const f32x4*)&W[(size_t)(bk * 64 + r) * NDIM + bn * 64 + c4];
    tile[r][c4 + 0] = v.x; tile[r][c4 + 1] = v.y;
    tile[r][c4 + 2] = v.z; tile[r][c4 + 3] = v.w;
  }
  __syncthreads();
#pragma unroll
  for (int j = 0; j < 2; ++j) {
    const int n  = j * 32 + (t >> 3);
    const int kb = (t & 7) * 8;
    u16x8 o;
#pragma unroll
    for (int q = 0; q < 8; ++q) o[q] = f2bf(tile[kb + q][n]);
    *(u16x8*)&WT[(size_t)(bn * 64 + n) * KDIM + bk * 64 + kb] = o;
  }
}

// ---------------------------------------------------------------------------
// LayerNorm: one wave per row of 512 f32 -> bf16
// ---------------------------------------------------------------------------
__global__ __launch_bounds__(256, 4) void ln_kernel(const float* __restrict__ x,
                                                    const float* __restrict__ gamma,
                                                    const float* __restrict__ beta,
                                                    unsigned short* __restrict__ h) {
  const int w = threadIdx.x >> 6, l = threadIdx.x & 63;
  const size_t row = (size_t)blockIdx.x * 4 + w;
  const float* xr = x + row * E + l * 8;
  const f32x4 v0 = *(const f32x4*)xr;
  const f32x4 v1 = *(const f32x4*)(xr + 4);
  float xv[8] = {v0.x, v0.y, v0.z, v0.w, v1.x, v1.y, v1.z, v1.w};
  float s = 0.f, q = 0.f;
#pragma unroll
  for (int j = 0; j < 8; ++j) { s += xv[j]; q += xv[j] * xv[j]; }
#pragma unroll
  for (int off = 32; off > 0; off >>= 1) {
    s += __shfl_xor(s, off);
    q += __shfl_xor(q, off);
  }
  const float mean = s * (1.0f / E);
  const float var  = q * (1.0f / E) - mean * mean;
  const float rstd = rsqrtf(var + 1e-6f);
  const f32x4 g0 = *(const f32x4*)(gamma + l * 8);
  const f32x4 g1 = *(const f32x4*)(gamma + l * 8 + 4);
  const f32x4 b0 = *(const f32x4*)(beta + l * 8);
  const f32x4 b1 = *(const f32x4*)(beta + l * 8 + 4);
  const float gv[8] = {g0.x, g0.y, g0.z, g0.w, g1.x, g1.y, g1.z, g1.w};
  const float bv[8] = {b0.x, b0.y, b0.z, b0.w, b1.x, b1.y, b1.z, b1.w};
  u16x8 o;
#pragma unroll
  for (int j = 0; j < 8; ++j) o[j] = f2bf((xv[j] - mean) * rstd * gv[j] + bv[j]);
  *(u16x8*)(h + row * E + l * 8) = o;
}

// ---------------------------------------------------------------------------
// GEMM: A[h, 16384 x 2048 bf16] x WT[512 x 2048 bf16] -> out f32, + bias+gelu
// 128x128 tile, BK=64, 4 waves (2x2), mfma_f32_16x16x32_bf16
// Staging: global_load_lds (16B/lane), LINEAR LDS dest + PRE-SWIZZLED global
// source (rule #21): LDS[r*128 + c'] = A[r][c' ^ ((r&7)<<4)], so the ds_read
// side keeps the T2 XOR swizzle and content is identical to reg-staged ver.
// Double-buffered, one __syncthreads per K-step (m97 structure, ~900 TF class)
// ---------------------------------------------------------------------------
#define NT (KDIM / 64)   // 32 K-steps

__global__ __launch_bounds__(256, 2) void gemm_kernel(const unsigned short* __restrict__ A,
                                                      const unsigned short* __restrict__ Bt,
                                                      const float* __restrict__ bias,
                                                      float* __restrict__ out) {
  __shared__ char smem[2 * 32768];   // buf{0,1}: A 16KB + B 16KB
  const int tid = threadIdx.x;
  const int l = tid & 63, w = tid >> 6;
  const int l7 = l & 7, l15 = l & 15, lhi = l >> 4;
  const int wr = w >> 1, wc = w & 1;

  const int bn = blockIdx.x & 3;         // 4 N-tiles
  const int bm = blockIdx.x >> 2;
  const size_t arow0 = (size_t)bm * 128;
  const int    brow0 = bn * 128;

  // staging geometry: wave w, call i covers rows {i*32 + w*8 + (l>>3)};
  // lane lands at LDS byte (row*128 + (l&7)*16); source col is pre-swizzled.
  const int srow = w * 8 + (l >> 3);
  const int swz  = (l7 * 16) ^ ((l >> 3) << 4);   // swizzled source byte col
  const char* gAb = (const char*)A  + ((size_t)(arow0 + srow) * KDIM) * 2 + swz;
  const char* gBb = (const char*)Bt + ((size_t)(brow0 + srow) * KDIM) * 2 + swz;

  auto stage = [&](int buf, int t) {
    char* base = smem + buf * 32768;
    const char* pa = gAb + (size_t)t * 128;
    const char* pb = gBb + (size_t)t * 128;
#pragma unroll
    for (int i = 0; i < 4; ++i) {
      gload16(pa + (size_t)i * 32 * KDIM * 2, base + (i * 32 + w * 8) * 128);
      gload16(pb + (size_t)i * 32 * KDIM * 2, base + 16384 + (i * 32 + w * 8) * 128);
    }
  };

  f32x4 acc[4][4];
#pragma unroll
  for (int m = 0; m < 4; ++m)
#pragma unroll
    for (int n = 0; n < 4; ++n) acc[m][n] = (f32x4){0.f, 0.f, 0.f, 0.f};

  // frag-read swizzled k-byte for kk=0; kk=1 flips bit 6 (outside swizzle bits)
  const int cs0 = (lhi * 16) ^ (l7 * 16);

  stage(0, 0);
  __syncthreads();

  for (int t = 0; t < NT; ++t) {
    if (t + 1 < NT) stage((t + 1) & 1, t + 1);
    const char* Ab = smem + (t & 1) * 32768;
    const char* Bb = Ab + 16384;
#pragma unroll
    for (int kk = 0; kk < 2; ++kk) {
      const int co = cs0 ^ (kk * 64);
      bf16x8 av[4], bv[4];
#pragma unroll
      for (int m = 0; m < 4; ++m)
        av[m] = *(const bf16x8*)(Ab + (wr * 64 + m * 16 + l15) * 128 + co);
#pragma unroll
      for (int n = 0; n < 4; ++n)
        bv[n] = *(const bf16x8*)(Bb + (wc * 64 + n * 16 + l15) * 128 + co);
#pragma unroll
      for (int m = 0; m < 4; ++m)
#pragma unroll
        for (int n = 0; n < 4; ++n)
          acc[m][n] = __builtin_amdgcn_mfma_f32_16x16x32_bf16(av[m], bv[n], acc[m][n], 0, 0, 0);
    }
    __syncthreads();   // drains vmcnt (stage for t+1) + all waves done with buf t
  }

  // epilogue: bias + exact gelu, f32 store
  // C/D layout (verified m89): col = l&15, row = (l>>4)*4 + reg
#pragma unroll
  for (int n = 0; n < 4; ++n) {
    const int col = brow0 + wc * 64 + n * 16 + l15;
    const float bb = bias[col];
#pragma unroll
    for (int m = 0; m < 4; ++m) {
      const size_t rbase = arow0 + wr * 64 + m * 16 + lhi * 4;
#pragma unroll
      for (int r = 0; r < 4; ++r) {
        const float v = acc[m][n][r] + bb;
        const float ge = 0.5f * v * (1.0f + erff(v * 0.70710678118654752f));
        out[(rbase + r) * NDIM + col] = ge;
      }
    }
  }
}

// ---------------------------------------------------------------------------
extern "C" void kernel_launch(void* const* d_in, const int* in_sizes, int n_in,
                              void* d_out, int out_size, void* d_ws, size_t ws_size,
                              hipStream_t stream) {
  const float* x     = (const float*)d_in[0];
  const float* gamma = (const float*)d_in[1];
  const float* beta  = (const float*)d_in[2];
  const float* W     = (const float*)d_in[3];
  const float* bias  = (const float*)d_in[4];
  float* out = (float*)d_out;

  unsigned short* WT = (unsigned short*)d_ws;          // 2 MiB
  const size_t wtBytes = (size_t)NDIM * KDIM * 2;
  unsigned short* h = (unsigned short*)((char*)d_ws + wtBytes);

  // chunk M if workspace can't hold the full 64 MiB h buffer
  int NC = 1;
  while (NC < 64 && wtBytes + ((size_t)MROWS / NC) * KDIM * 2 > ws_size) NC <<= 1;
  const int Mc = MROWS / NC;

  wt_kernel<<<256, 256, 0, stream>>>(W, WT);
  for (int c = 0; c < NC; ++c) {
    const float* xc = x + (size_t)c * Mc * KDIM;       // Mc*4 x-rows * 512
    ln_kernel<<<Mc, 256, 0, stream>>>(xc, gamma, beta, h);
    gemm_kernel<<<(Mc / 128) * 4, 256, 0, stream>>>(h, WT, bias,
                                                    out + (size_t)c * Mc * NDIM);
  }
}